// Round 1
// baseline (3548.211 us; speedup 1.0000x reference)
//
#include <hip/hip_runtime.h>
#include <hip/hip_bf16.h>

#define T_LEN 1024
#define BATCH 32
#define HIDN  256
#define VOCAB 5000
#define MROWS (BATCH * T_LEN)                    // 32768
#define OUT_ELEMS ((size_t)MROWS * VOCAB)        // 163,840,000
#define PRE_ELEMS ((size_t)MROWS * HIDN)         // 8,388,608
#define HS_BYTES  ((size_t)MROWS * HIDN * 2)     // 16,777,216

#define NCONS    254   // consumer blocks in fused kernel
#define NB_TILES 40    // ceil(VOCAB/128)
#define DEFER_MB 242   // out tiles with mb>=242 overlap the pre tail; run post-scan

typedef __bf16 bf16x8 __attribute__((ext_vector_type(8)));
typedef float  f32x4  __attribute__((ext_vector_type(4)));

// Verified gfx950 layouts (learn_hip m89/m120):
//   A-frag: lane holds A[m=lane&15][k=(lane>>4)*8+j]
//   B-frag: lane holds B[k=(lane>>4)*8+j][n=lane&15]
//   C/D   : lane,reg -> row m=(lane>>4)*4+reg, col n=lane&15
__device__ __forceinline__ f32x4 mfma16(bf16x8 a, bf16x8 b, f32x4 c) {
    return __builtin_amdgcn_mfma_f32_16x16x32_bf16(a, b, c, 0, 0, 0);
}

// 8 consecutive fp32 -> bf16x8 (two aligned 16B loads + cvt)
__device__ __forceinline__ bf16x8 cvt8(const float* p) {
    f32x4 f0 = *(const f32x4*)p;
    f32x4 f1 = *(const f32x4*)(p + 4);
    bf16x8 v;
    v[0] = (__bf16)f0[0]; v[1] = (__bf16)f0[1]; v[2] = (__bf16)f0[2]; v[3] = (__bf16)f0[3];
    v[4] = (__bf16)f1[0]; v[5] = (__bf16)f1[1]; v[6] = (__bf16)f1[2]; v[7] = (__bf16)f1[3];
    return v;
}

__device__ __forceinline__ float tanh_fast(float x) {
    float ax = __builtin_fabsf(x);
    if (__builtin_expect(ax > 0.55f, 0)) return tanhf(x);  // |z| ~ 0.025 here; rare
    float x2 = x * x;
    float q = fmaf(x2, 0.021869488f, -0.053968254f);
    q = fmaf(x2, q, 0.13333334f);
    q = fmaf(x2, q, -0.33333334f);
    return fmaf(x * x2, q, x);
}

// padding_idx=0 zeroing + progress-counter reset (idempotent per launch)
__global__ void init_misc(float* emb, int* ctr) {
    int i = threadIdx.x;
    if (i < HIDN) emb[i] = 0.0f;
    if (ctr != nullptr && i < 2) ctr[i] = 0;
}

// C[m][n] = sum_k A[m][k]*W[n][k] + bias[n];  A fp32-gathered (pre) or bf16 (decode).
// 128x128 tile, BK=32, 4 waves of 64x64. LDS rows padded to 40 elems.
template <bool AFP32>
__global__ __launch_bounds__(256, 2) void gemm_bias(
    const void* __restrict__ Abase, const int* __restrict__ idx,
    const float* __restrict__ W, int wstride,
    const float* __restrict__ bias,
    float* __restrict__ outp, int N, int ostride)
{
    __shared__ __align__(16) __bf16 At[128 * 40];
    __shared__ __align__(16) __bf16 Bt[128 * 40];
    const int tid  = threadIdx.x;
    const int lane = tid & 63;
    const int wv   = tid >> 6;
    const int m0   = blockIdx.y * 128;
    const int n0   = blockIdx.x * 128;
    const int moff = (wv & 1) * 64;
    const int noff = (wv >> 1) * 64;
    const int c15  = lane & 15;
    const int q    = lane >> 4;

    f32x4 acc[4][4];
#pragma unroll
    for (int i = 0; i < 4; i++)
#pragma unroll
        for (int j = 0; j < 4; j++) acc[i][j] = f32x4{0.f, 0.f, 0.f, 0.f};

    const int srow = tid >> 2;   // 0..63
    const int sc   = tid & 3;    // 8-elem chunk within 32-elem row

    for (int k0 = 0; k0 < HIDN; k0 += 32) {
#pragma unroll
        for (int i = 0; i < 2; i++) {
            int row = srow + i * 64;
            size_t arow = (idx != nullptr) ? (size_t)idx[m0 + row] : (size_t)(m0 + row);
            if constexpr (AFP32) {
                bf16x8 av = cvt8((const float*)Abase + arow * HIDN + k0 + sc * 8);
                *(bf16x8*)&At[row * 40 + sc * 8] = av;
            } else {
                uint4 av = *(const uint4*)((const __bf16*)Abase + arow * HIDN + k0 + sc * 8);
                *(uint4*)&At[row * 40 + sc * 8] = av;
            }
            int wrow = n0 + row; if (wrow >= N) wrow = N - 1;   // clamp; masked at store
            bf16x8 wv8 = cvt8(W + (size_t)wrow * wstride + k0 + sc * 8);
            *(bf16x8*)&Bt[row * 40 + sc * 8] = wv8;
        }
        __syncthreads();
        bf16x8 af[4], bfv[4];
#pragma unroll
        for (int mt = 0; mt < 4; mt++)
            af[mt] = *(const bf16x8*)&At[(moff + mt * 16 + c15) * 40 + q * 8];
#pragma unroll
        for (int nt = 0; nt < 4; nt++)
            bfv[nt] = *(const bf16x8*)&Bt[(noff + nt * 16 + c15) * 40 + q * 8];
#pragma unroll
        for (int mt = 0; mt < 4; mt++)
#pragma unroll
            for (int nt = 0; nt < 4; nt++)
                acc[mt][nt] = mfma16(af[mt], bfv[nt], acc[mt][nt]);
        __syncthreads();
    }

    float bv[4];
#pragma unroll
    for (int nt = 0; nt < 4; nt++) {
        int n = n0 + noff + nt * 16 + c15;
        bv[nt] = bias[n < N ? n : N - 1];
    }
#pragma unroll
    for (int mt = 0; mt < 4; mt++)
#pragma unroll
        for (int nt = 0; nt < 4; nt++) {
            int n = n0 + noff + nt * 16 + c15;
#pragma unroll
            for (int r = 0; r < 4; r++) {
                int m = m0 + moff + mt * 16 + q * 4 + r;
                if (n < N) outp[(size_t)m * ostride + n] = acc[mt][nt][r] + bv[nt];
            }
        }
}

// ---------------- legacy standalone scan (fallback path only) ----------------
__global__ __launch_bounds__(512, 1) void rnn_scan(
    const float* __restrict__ pre, const float* __restrict__ W1,
    __bf16* __restrict__ hs, float* __restrict__ hT)
{
    __shared__ __align__(16) __bf16 hbuf[2][16][264];
    const int tid  = threadIdx.x;
    const int lane = tid & 63;
    const int wv   = tid >> 6;        // 0..7
    const int b0   = blockIdx.x * 16;
    const int q    = lane >> 4;
    const int c15  = lane & 15;

    for (int i = tid; i < 2 * 16 * 264; i += 512) ((__bf16*)hbuf)[i] = (__bf16)0.0f;

    bf16x8 bfrag[2][8];
#pragma unroll
    for (int nt = 0; nt < 2; nt++) {
        int n = wv * 32 + nt * 16 + c15;
        const float* base = W1 + (size_t)n * (2 * HIDN) + HIDN;
#pragma unroll
        for (int ks = 0; ks < 8; ks++)
            bfrag[nt][ks] = cvt8(base + ks * 32 + q * 8);
    }

    const float* pbase[8];
    __bf16*      hbase[8];
#pragma unroll
    for (int nt = 0; nt < 2; nt++)
#pragma unroll
        for (int r = 0; r < 4; r++) {
            int m = 4 * q + r;
            int n = wv * 32 + nt * 16 + c15;
            pbase[nt * 4 + r] = pre + (size_t)(b0 + m) * T_LEN * HIDN + n;
            hbase[nt * 4 + r] = hs  + (size_t)(b0 + m) * T_LEN * HIDN + n;
        }

    float pf[2][8];
#pragma unroll
    for (int i = 0; i < 8; i++) { pf[0][i] = pbase[i][0]; pf[1][i] = pbase[i][HIDN]; }

    __syncthreads();

    for (int t0 = 0; t0 < T_LEN; t0 += 2) {
#pragma unroll
        for (int half = 0; half < 2; half++) {
            const int t = t0 + half;
            const int cur = half;
            float pv[8];
#pragma unroll
            for (int i = 0; i < 8; i++) pv[i] = pf[cur][i];
            if (t + 2 < T_LEN) {
#pragma unroll
                for (int i = 0; i < 8; i++) pf[cur][i] = pbase[i][(size_t)(t + 2) * HIDN];
            }

            bf16x8 af[8];
#pragma unroll
            for (int ks = 0; ks < 8; ks++)
                af[ks] = *(const bf16x8*)&hbuf[cur][c15][ks * 32 + q * 8];

            f32x4 a0 = f32x4{0.f, 0.f, 0.f, 0.f};
            f32x4 a1 = f32x4{0.f, 0.f, 0.f, 0.f};
#pragma unroll
            for (int ks = 0; ks < 8; ks++) {
                a0 = mfma16(af[ks], bfrag[0][ks], a0);
                a1 = mfma16(af[ks], bfrag[1][ks], a1);
            }

#pragma unroll
            for (int nt = 0; nt < 2; nt++) {
                f32x4 a = nt ? a1 : a0;
                int n = wv * 32 + nt * 16 + c15;
#pragma unroll
                for (int r = 0; r < 4; r++) {
                    float x  = a[r] + pv[nt * 4 + r];
                    float th = tanh_fast(x);
                    __bf16 hb = (__bf16)th;
                    hbuf[cur ^ 1][4 * q + r][n] = hb;
                    hbase[nt * 4 + r][(size_t)t * HIDN] = hb;
                    if (t == T_LEN - 1)
                        hT[(size_t)(b0 + 4 * q + r) * HIDN + n] = th;
                }
            }
            __syncthreads();
        }
    }
}

// ---------------- fused producer/consumer kernel ----------------

// Spin until both scan blocks have published >= need. Agent-scope acquire:
// emits buffer_inv (per-CU L1 + per-XCD L2) so cross-XCD/cross-iteration hs
// reads after the barrier see fresh data.
__device__ __forceinline__ void wait_both(int* ctr, int need) {
    if (threadIdx.x == 0) {
        while (__hip_atomic_load(&ctr[0], __ATOMIC_ACQUIRE, __HIP_MEMORY_SCOPE_AGENT) < need ||
               __hip_atomic_load(&ctr[1], __ATOMIC_ACQUIRE, __HIP_MEMORY_SCOPE_AGENT) < need)
            __builtin_amdgcn_s_sleep(32);   // ~2k cycles between polls
    }
    __syncthreads();
}

// One 128x128 decode tile, 512 threads (8 waves: 2m x 4n of 64x32 each).
__device__ __forceinline__ void decode_tile(
    const __bf16* __restrict__ hs, const float* __restrict__ Wd,
    const float* __restrict__ bd, float* __restrict__ out,
    int mb, int nb, __bf16* At, __bf16* Bt)
{
    const int tid  = threadIdx.x;
    const int lane = tid & 63;
    const int wvv  = tid >> 6;          // 0..7
    const int m0   = mb * 128;
    const int n0   = nb * 128;
    const int moff = (wvv & 1) * 64;
    const int noff = (wvv >> 1) * 32;
    const int c15  = lane & 15;
    const int q    = lane >> 4;

    f32x4 acc[4][2];
#pragma unroll
    for (int i = 0; i < 4; i++)
#pragma unroll
        for (int j = 0; j < 2; j++) acc[i][j] = f32x4{0.f, 0.f, 0.f, 0.f};

    const int srow = tid >> 2;          // 0..127
    const int sc   = tid & 3;

    for (int k0 = 0; k0 < HIDN; k0 += 32) {
        uint4 av = *(const uint4*)(hs + (size_t)(m0 + srow) * HIDN + k0 + sc * 8);
        *(uint4*)&At[srow * 40 + sc * 8] = av;
        int wrow = n0 + srow; if (wrow >= VOCAB) wrow = VOCAB - 1;  // clamp; masked at store
        *(bf16x8*)&Bt[srow * 40 + sc * 8] = cvt8(Wd + (size_t)wrow * HIDN + k0 + sc * 8);
        __syncthreads();
        bf16x8 af[4], bfv[2];
#pragma unroll
        for (int mt = 0; mt < 4; mt++)
            af[mt] = *(const bf16x8*)&At[(moff + mt * 16 + c15) * 40 + q * 8];
#pragma unroll
        for (int nt = 0; nt < 2; nt++)
            bfv[nt] = *(const bf16x8*)&Bt[(noff + nt * 16 + c15) * 40 + q * 8];
#pragma unroll
        for (int mt = 0; mt < 4; mt++)
#pragma unroll
            for (int nt = 0; nt < 2; nt++)
                acc[mt][nt] = mfma16(af[mt], bfv[nt], acc[mt][nt]);
        __syncthreads();
    }

    float bv[2];
#pragma unroll
    for (int nt = 0; nt < 2; nt++) {
        int n = n0 + noff + nt * 16 + c15;
        bv[nt] = bd[n < VOCAB ? n : VOCAB - 1];
    }
#pragma unroll
    for (int mt = 0; mt < 4; mt++)
#pragma unroll
        for (int nt = 0; nt < 2; nt++) {
            int n = n0 + noff + nt * 16 + c15;
            if (n < VOCAB) {
#pragma unroll
                for (int r = 0; r < 4; r++) {
                    int m = m0 + moff + mt * 16 + q * 4 + r;
                    out[(size_t)m * VOCAB + n] = acc[mt][nt][r] + bv[nt];
                }
            }
        }
}

// Grid = 256 blocks x 512 threads: blocks 0-1 run the RNN scan (producers),
// blocks 2-255 run the decode GEMM (consumers), gated per 128-step chunk on
// device-scope progress counters. 256 blocks <= 256 CUs => all co-resident,
// producers never wait on consumers => no deadlock.
// pre lives at the TAIL of out (rows >= 31090); only tiles mb >= DEFER_MB
// write there, and those are deferred until the scan fully completes.
__global__ __launch_bounds__(512, 1) void fused_scan_decode(
    const float* __restrict__ pre, const float* __restrict__ W1,
    __bf16* __restrict__ hs, float* __restrict__ hT,
    const float* __restrict__ Wd, const float* __restrict__ bd,
    float* __restrict__ out, int* __restrict__ ctr)
{
    __shared__ __align__(16) char smem[20480];   // max(scan 16896, decode 2*10240)
    const int tid  = threadIdx.x;
    const int lane = tid & 63;
    const int wv   = tid >> 6;
    const int c15  = lane & 15;
    const int q    = lane >> 4;

    if (blockIdx.x < 2) {
        // ----------------- producer: sequential RNN scan -----------------
        __bf16 (*hbuf)[16][264] = reinterpret_cast<__bf16 (*)[16][264]>(smem);
        const int b0 = blockIdx.x * 16;

        for (int i = tid; i < 2 * 16 * 264; i += 512) ((__bf16*)smem)[i] = (__bf16)0.0f;

        bf16x8 bfrag[2][8];
#pragma unroll
        for (int nt = 0; nt < 2; nt++) {
            int n = wv * 32 + nt * 16 + c15;
            const float* base = W1 + (size_t)n * (2 * HIDN) + HIDN;
#pragma unroll
            for (int ks = 0; ks < 8; ks++)
                bfrag[nt][ks] = cvt8(base + ks * 32 + q * 8);
        }

        const float* pbase[8];
        __bf16*      hbase[8];
#pragma unroll
        for (int nt = 0; nt < 2; nt++)
#pragma unroll
            for (int r = 0; r < 4; r++) {
                int m = 4 * q + r;
                int n = wv * 32 + nt * 16 + c15;
                pbase[nt * 4 + r] = pre + (size_t)(b0 + m) * T_LEN * HIDN + n;
                hbase[nt * 4 + r] = hs  + (size_t)(b0 + m) * T_LEN * HIDN + n;
            }

        float pf[2][8];
#pragma unroll
        for (int i = 0; i < 8; i++) { pf[0][i] = pbase[i][0]; pf[1][i] = pbase[i][HIDN]; }

        __syncthreads();

        for (int t0 = 0; t0 < T_LEN; t0 += 2) {
#pragma unroll
            for (int half = 0; half < 2; half++) {
                const int t = t0 + half;
                const int cur = half;                 // compile-time buffer index
                float pv[8];
#pragma unroll
                for (int i = 0; i < 8; i++) pv[i] = pf[cur][i];
                if (t + 2 < T_LEN) {
#pragma unroll
                    for (int i = 0; i < 8; i++) pf[cur][i] = pbase[i][(size_t)(t + 2) * HIDN];
                }

                bf16x8 af[8];
#pragma unroll
                for (int ks = 0; ks < 8; ks++)
                    af[ks] = *(const bf16x8*)&hbuf[cur][c15][ks * 32 + q * 8];

                f32x4 a0 = f32x4{0.f, 0.f, 0.f, 0.f};
                f32x4 a1 = f32x4{0.f, 0.f, 0.f, 0.f};
#pragma unroll
                for (int ks = 0; ks < 8; ks++) {
                    a0 = mfma16(af[ks], bfrag[0][ks], a0);
                    a1 = mfma16(af[ks], bfrag[1][ks], a1);
                }

#pragma unroll
                for (int nt = 0; nt < 2; nt++) {
                    f32x4 a = nt ? a1 : a0;
                    int n = wv * 32 + nt * 16 + c15;
#pragma unroll
                    for (int r = 0; r < 4; r++) {
                        float x  = a[r] + pv[nt * 4 + r];
                        float th = tanh_fast(x);
                        __bf16 hb = (__bf16)th;
                        hbuf[cur ^ 1][4 * q + r][n] = hb;          // next step's A operand
                        hbase[nt * 4 + r][(size_t)t * HIDN] = hb;  // hs for decode GEMM
                        if (t == T_LEN - 1)
                            hT[(size_t)(b0 + 4 * q + r) * HIDN + n] = th;
                    }
                }
                __syncthreads();
            }

            // Publish progress every 128 steps. threadfence() (agent scope)
            // drains vmcnt + writes back this XCD's L2 so consumers on other
            // XCDs see the hs rows; then a single release store of the count.
            if (((t0 + 2) & 127) == 0) {
                __threadfence();
                __syncthreads();
                if (tid == 0)
                    __hip_atomic_store(&ctr[blockIdx.x], t0 + 2,
                                       __ATOMIC_RELEASE, __HIP_MEMORY_SCOPE_AGENT);
            }
        }
    } else {
        // ----------------- consumer: decode GEMM over ready chunks -----------------
        __bf16* At = (__bf16*)smem;             // 128*40 bf16 = 10240 B
        __bf16* Bt = (__bf16*)(smem + 10240);
        const int cid = (int)blockIdx.x - 2;    // 0..253

        for (int c = 0; c < 8; ++c) {
            wait_both(ctr, (c + 1) * 128);
            for (int idx = cid; idx < 32 * NB_TILES; idx += NCONS) {
                int b  = idx / NB_TILES;
                int nb = idx - b * NB_TILES;
                int mb = b * 8 + c;             // tile rows = batch b, t in [c*128, c*128+128)
                if (mb >= DEFER_MB) continue;   // would clobber live pre; deferred
                decode_tile(hs, Wd, bd, out, mb, nb, At, Bt);
            }
        }

        // Deferred tiles (mb 242..255, 560 tiles): pre is fully dead once both
        // counters reach T_LEN.
        wait_both(ctr, T_LEN);
        for (int idx = cid; idx < 560; idx += NCONS) {
            int mb, nb;
            if (idx < 240) { mb = 242 + idx / NB_TILES; nb = idx % NB_TILES; }
            else { int j = idx - 240; mb = 248 + j / NB_TILES; nb = j % NB_TILES; }
            decode_tile(hs, Wd, bd, out, mb, nb, At, Bt);
        }
    }
}

extern "C" void kernel_launch(void* const* d_in, const int* in_sizes, int n_in,
                              void* d_out, int out_size, void* d_ws, size_t ws_size,
                              hipStream_t stream)
{
    const int*   x   = (const int*)d_in[0];
    float*       emb = (float*)d_in[1];          // row 0 zeroed (padding_idx)
    const float* W1  = (const float*)d_in[2];    // [256][512]
    const float* b1  = (const float*)d_in[3];
    const float* Wd  = (const float*)d_in[4];    // [5000][256]
    const float* bd  = (const float*)d_in[5];
    float* out = (float*)d_out;
    __bf16* hs = (__bf16*)d_ws;                  // bf16 hidden history, 16.8 MB

    if (ws_size >= HS_BYTES + 8) {
        // Fused path: progress counters in ws just past hs (never clobbered);
        // pre (fp32, 33.5 MB) at the TAIL of out — only deferred tiles touch it.
        int*   ctr = (int*)((char*)d_ws + HS_BYTES);
        float* pre = out + (OUT_ELEMS - PRE_ELEMS);

        init_misc<<<1, 256, 0, stream>>>(emb, ctr);
        // pre[b*T+t][j] = b1[j] + sum_k emb[x[b,t]][k] * W1[j][k]   (xt half of W1)
        gemm_bias<true><<<dim3(2, 256), 256, 0, stream>>>(
            (const void*)emb, x, W1, 2 * HIDN, b1, pre, HIDN, HIDN);
        // blocks 0-1: scan (producers); blocks 2-255: decode (consumers)
        fused_scan_decode<<<256, 512, 0, stream>>>(
            pre, W1, hs, out + OUT_ELEMS, Wd, bd, out, ctr);
    } else {
        // Legacy serial path (previous session's kernel), if ws is too small.
        float* pre = (float*)d_out;              // aliases out head; dead before decode
        init_misc<<<1, 256, 0, stream>>>(emb, nullptr);
        gemm_bias<true><<<dim3(2, 256), 256, 0, stream>>>(
            (const void*)emb, x, W1, 2 * HIDN, b1, pre, HIDN, HIDN);
        rnn_scan<<<2, 512, 0, stream>>>(pre, W1, hs, out + OUT_ELEMS);
        gemm_bias<false><<<dim3(40, 256), 256, 0, stream>>>(
            (const void*)hs, nullptr, Wd, HIDN, bd, out, VOCAB, VOCAB);
    }
}

// Round 2
// 1863.672 us; speedup vs baseline: 1.9039x; 1.9039x over previous
//
#include <hip/hip_runtime.h>
#include <hip/hip_bf16.h>

#define T_LEN 1024
#define BATCH 32
#define HIDN  256
#define VOCAB 5000
#define MROWS (BATCH * T_LEN)                    // 32768
#define OUT_ELEMS ((size_t)MROWS * VOCAB)        // 163,840,000
#define PRE_ELEMS ((size_t)MROWS * HIDN)         // 8,388,608
#define HS_BYTES  ((size_t)MROWS * HIDN * 2)     // 16,777,216
#define WD_BYTES  ((size_t)VOCAB * HIDN * 2)     // 2,560,000

typedef __bf16 bf16x8 __attribute__((ext_vector_type(8)));
typedef float  f32x4  __attribute__((ext_vector_type(4)));
typedef __attribute__((address_space(3))) uint32_t       lds_u32;
typedef __attribute__((address_space(1))) const uint32_t glb_u32;

// Verified gfx950 layouts (learn_hip m89/m120):
//   A-frag: lane holds A[m=lane&15][k=(lane>>4)*8+j]
//   B-frag: lane holds B[k=(lane>>4)*8+j][n=lane&15]
//   C/D   : lane,reg -> row m=(lane>>4)*4+reg, col n=lane&15
__device__ __forceinline__ f32x4 mfma16(bf16x8 a, bf16x8 b, f32x4 c) {
    return __builtin_amdgcn_mfma_f32_16x16x32_bf16(a, b, c, 0, 0, 0);
}

// 8 consecutive fp32 -> bf16x8 (two aligned 16B loads + cvt)
__device__ __forceinline__ bf16x8 cvt8(const float* p) {
    f32x4 f0 = *(const f32x4*)p;
    f32x4 f1 = *(const f32x4*)(p + 4);
    bf16x8 v;
    v[0] = (__bf16)f0[0]; v[1] = (__bf16)f0[1]; v[2] = (__bf16)f0[2]; v[3] = (__bf16)f0[3];
    v[4] = (__bf16)f1[0]; v[5] = (__bf16)f1[1]; v[6] = (__bf16)f1[2]; v[7] = (__bf16)f1[3];
    return v;
}

__device__ __forceinline__ float tanh_fast(float x) {
    float ax = __builtin_fabsf(x);
    if (__builtin_expect(ax > 0.55f, 0)) return tanhf(x);  // |z| ~ 0.025 here; rare
    float x2 = x * x;
    float q = fmaf(x2, 0.021869488f, -0.053968254f);
    q = fmaf(x2, q, 0.13333334f);
    q = fmaf(x2, q, -0.33333334f);
    return fmaf(x * x2, q, x);
}

// padding_idx=0 (idempotent; harness restores d_in each launch)
__global__ void zero_emb_row0(float* emb) {
    int i = threadIdx.x;
    if (i < HIDN) emb[i] = 0.0f;
}

// One-time Wd fp32 -> bf16 (5000x256 = 1.28M elems, 8/thread, 625 blocks)
__global__ void wd_convert(const float* __restrict__ Wd, __bf16* __restrict__ wdb) {
    size_t i = ((size_t)blockIdx.x * 256 + threadIdx.x) * 8;
    *(bf16x8*)(wdb + i) = cvt8(Wd + i);
}

// C[m][n] = sum_k A[m][k]*W[n][k] + bias[n];  A fp32-gathered (pre) or bf16 (decode).
// 128x128 tile, BK=32, 4 waves of 64x64. LDS rows padded to 40 elems.
// <true> used for the pre-GEMM; <false> kept only as decode fallback (small ws).
template <bool AFP32>
__global__ __launch_bounds__(256, 2) void gemm_bias(
    const void* __restrict__ Abase, const int* __restrict__ idx,
    const float* __restrict__ W, int wstride,
    const float* __restrict__ bias,
    float* __restrict__ outp, int N, int ostride)
{
    __shared__ __align__(16) __bf16 At[128 * 40];
    __shared__ __align__(16) __bf16 Bt[128 * 40];
    const int tid  = threadIdx.x;
    const int lane = tid & 63;
    const int wv   = tid >> 6;
    const int m0   = blockIdx.y * 128;
    const int n0   = blockIdx.x * 128;
    const int moff = (wv & 1) * 64;
    const int noff = (wv >> 1) * 64;
    const int c15  = lane & 15;
    const int q    = lane >> 4;

    f32x4 acc[4][4];
#pragma unroll
    for (int i = 0; i < 4; i++)
#pragma unroll
        for (int j = 0; j < 4; j++) acc[i][j] = f32x4{0.f, 0.f, 0.f, 0.f};

    const int srow = tid >> 2;   // 0..63
    const int sc   = tid & 3;    // 8-elem chunk within 32-elem row

    for (int k0 = 0; k0 < HIDN; k0 += 32) {
#pragma unroll
        for (int i = 0; i < 2; i++) {
            int row = srow + i * 64;
            size_t arow = (idx != nullptr) ? (size_t)idx[m0 + row] : (size_t)(m0 + row);
            if constexpr (AFP32) {
                bf16x8 av = cvt8((const float*)Abase + arow * HIDN + k0 + sc * 8);
                *(bf16x8*)&At[row * 40 + sc * 8] = av;
            } else {
                uint4 av = *(const uint4*)((const __bf16*)Abase + arow * HIDN + k0 + sc * 8);
                *(uint4*)&At[row * 40 + sc * 8] = av;
            }
            int wrow = n0 + row; if (wrow >= N) wrow = N - 1;   // clamp; masked at store
            bf16x8 wv8 = cvt8(W + (size_t)wrow * wstride + k0 + sc * 8);
            *(bf16x8*)&Bt[row * 40 + sc * 8] = wv8;
        }
        __syncthreads();
        bf16x8 af[4], bfv[4];
#pragma unroll
        for (int mt = 0; mt < 4; mt++)
            af[mt] = *(const bf16x8*)&At[(moff + mt * 16 + c15) * 40 + q * 8];
#pragma unroll
        for (int nt = 0; nt < 4; nt++)
            bfv[nt] = *(const bf16x8*)&Bt[(noff + nt * 16 + c15) * 40 + q * 8];
#pragma unroll
        for (int mt = 0; mt < 4; mt++)
#pragma unroll
            for (int nt = 0; nt < 4; nt++)
                acc[mt][nt] = mfma16(af[mt], bfv[nt], acc[mt][nt]);
        __syncthreads();
    }

    float bv[4];
#pragma unroll
    for (int nt = 0; nt < 4; nt++) {
        int n = n0 + noff + nt * 16 + c15;
        bv[nt] = bias[n < N ? n : N - 1];
    }
#pragma unroll
    for (int mt = 0; mt < 4; mt++)
#pragma unroll
        for (int nt = 0; nt < 4; nt++) {
            int n = n0 + noff + nt * 16 + c15;
#pragma unroll
            for (int r = 0; r < 4; r++) {
                int m = m0 + moff + mt * 16 + q * 4 + r;
                if (n < N) outp[(size_t)m * ostride + n] = acc[mt][nt][r] + bv[nt];
            }
        }
}

// ---------------- optimized decode GEMM (m97-style) ----------------
// out[m][n] = bd[n] + sum_k hs[m][k] * wd[n][k]; both operands bf16.
// 128x128 tile, BK=64, 4 waves (2m x 2n of 64x64), double-buffered LDS,
// global_load_lds width-16 staging. Both-sides XOR swizzle (rule #21):
// LDS dest stays linear; per-lane SOURCE chunk is pre-swizzled with the same
// involution the ds_read applies, so fragment reads are bank-conflict-free
// (8 distinct 16B slots x 4 banks, 2 lanes/slot = free per m136).
__device__ __forceinline__ void stage_tiles(
    const __bf16* __restrict__ hs, const __bf16* __restrict__ wd,
    int m0, int n0, int w, int lr, int xch, __bf16* Atb, __bf16* Btb, int k0)
{
#pragma unroll
    for (int j = 0; j < 4; ++j) {
        int ra = w * 32 + j * 8 + lr;         // tile row; ra&7 == lr
        __builtin_amdgcn_global_load_lds(
            (glb_u32*)(hs + (size_t)(m0 + ra) * HIDN + k0 + xch * 8),
            (lds_u32*)&Atb[(w * 32 + j * 8) * 64], 16, 0, 0);
        int rb = n0 + ra; if (rb >= VOCAB) rb = VOCAB - 1;   // clamp; masked at store
        __builtin_amdgcn_global_load_lds(
            (glb_u32*)(wd + (size_t)rb * HIDN + k0 + xch * 8),
            (lds_u32*)&Btb[(w * 32 + j * 8) * 64], 16, 0, 0);
    }
}

__global__ __launch_bounds__(256) void decode_gemm(
    const __bf16* __restrict__ hs, const __bf16* __restrict__ wd,
    const float* __restrict__ bd, float* __restrict__ out)
{
    __shared__ __align__(16) __bf16 At[2][128 * 64];   // 16 KiB each
    __shared__ __align__(16) __bf16 Bt[2][128 * 64];
    const int tid  = threadIdx.x;
    const int lane = tid & 63;
    const int w    = tid >> 6;
    const int c15  = lane & 15;
    const int q    = lane >> 4;
    const int m0   = blockIdx.y * 128;
    const int n0   = blockIdx.x * 128;
    const int moff = (w & 1) * 64;
    const int noff = (w >> 1) * 64;

    // staging geometry: wave w owns rows [w*32, w*32+32), 4 loads x 8 rows;
    // lane covers row lr = lane>>3, physical chunk lane&7. Source chunk is
    // (lane&7)^lr so that physical chunk p of row r holds logical chunk p^(r&7).
    const int lr  = lane >> 3;
    const int xch = (lane & 7) ^ lr;

    f32x4 acc[4][4];
#pragma unroll
    for (int i = 0; i < 4; i++)
#pragma unroll
        for (int j = 0; j < 4; j++) acc[i][j] = f32x4{0.f, 0.f, 0.f, 0.f};

    stage_tiles(hs, wd, m0, n0, w, lr, xch, At[0], Bt[0], 0);

#pragma unroll
    for (int t = 0; t < 4; ++t) {                 // K = 256 = 4 x BK64
        const int cur = t & 1;
        __syncthreads();                          // drains vmcnt (stage t) + lgkm (reads t-1)
        if (t < 3)
            stage_tiles(hs, wd, m0, n0, w, lr, xch, At[cur ^ 1], Bt[cur ^ 1], (t + 1) * 64);
        const __bf16* Ab = At[cur];
        const __bf16* Bb = Bt[cur];
#pragma unroll
        for (int ks = 0; ks < 2; ++ks) {          // BK64 = 2 x K32 MFMA slabs
            bf16x8 af[4], bfv[4];
#pragma unroll
            for (int mt = 0; mt < 4; ++mt) {
                int row = moff + mt * 16 + c15;
                int ch  = (ks * 4 + q) ^ (row & 7);   // un-swizzle on read
                af[mt] = *(const bf16x8*)&Ab[row * 64 + ch * 8];
            }
#pragma unroll
            for (int nt = 0; nt < 4; ++nt) {
                int row = noff + nt * 16 + c15;
                int ch  = (ks * 4 + q) ^ (row & 7);
                bfv[nt] = *(const bf16x8*)&Bb[row * 64 + ch * 8];
            }
#pragma unroll
            for (int mt = 0; mt < 4; ++mt)
#pragma unroll
                for (int nt = 0; nt < 4; ++nt)
                    acc[mt][nt] = mfma16(af[mt], bfv[nt], acc[mt][nt]);
        }
    }

    float bv[4];
#pragma unroll
    for (int nt = 0; nt < 4; ++nt) {
        int n = n0 + noff + nt * 16 + c15;
        bv[nt] = bd[n < VOCAB ? n : VOCAB - 1];
    }
#pragma unroll
    for (int mt = 0; mt < 4; ++mt)
#pragma unroll
        for (int nt = 0; nt < 4; ++nt) {
            int n = n0 + noff + nt * 16 + c15;
            if (n < VOCAB) {
#pragma unroll
                for (int r = 0; r < 4; ++r) {
                    int m = m0 + moff + mt * 16 + q * 4 + r;
                    out[(size_t)m * VOCAB + n] = acc[mt][nt][r] + bv[nt];
                }
            }
        }
}

// Sequential recurrence: 2 blocks x 16 batches, 8 waves; wave owns a 32-wide
// n-slice. W1h B-frags (bf16-converted) live in registers for the whole scan;
// h double-buffered in LDS (+8 row pad); pre prefetched 2 steps ahead.
// t-loop unrolled x2 so buffer index is compile-time.
__global__ __launch_bounds__(512, 1) void rnn_scan(
    const float* __restrict__ pre, const float* __restrict__ W1,
    __bf16* __restrict__ hs, float* __restrict__ hT)
{
    __shared__ __align__(16) __bf16 hbuf[2][16][264];
    const int tid  = threadIdx.x;
    const int lane = tid & 63;
    const int wv   = tid >> 6;        // 0..7
    const int b0   = blockIdx.x * 16;
    const int q    = lane >> 4;
    const int c15  = lane & 15;

    for (int i = tid; i < 2 * 16 * 264; i += 512) ((__bf16*)hbuf)[i] = (__bf16)0.0f;

    // B-frags: B[k][n] = W1[n][256+k],  n = wv*32 + nt*16 + c15
    bf16x8 bfrag[2][8];
#pragma unroll
    for (int nt = 0; nt < 2; nt++) {
        int n = wv * 32 + nt * 16 + c15;
        const float* base = W1 + (size_t)n * (2 * HIDN) + HIDN;
#pragma unroll
        for (int ks = 0; ks < 8; ks++)
            bfrag[nt][ks] = cvt8(base + ks * 32 + q * 8);
    }

    const float* pbase[8];
    __bf16*      hbase[8];
#pragma unroll
    for (int nt = 0; nt < 2; nt++)
#pragma unroll
        for (int r = 0; r < 4; r++) {
            int m = 4 * q + r;
            int n = wv * 32 + nt * 16 + c15;
            pbase[nt * 4 + r] = pre + (size_t)(b0 + m) * T_LEN * HIDN + n;
            hbase[nt * 4 + r] = hs  + (size_t)(b0 + m) * T_LEN * HIDN + n;
        }

    float pf[2][8];
#pragma unroll
    for (int i = 0; i < 8; i++) { pf[0][i] = pbase[i][0]; pf[1][i] = pbase[i][HIDN]; }

    __syncthreads();

    for (int t0 = 0; t0 < T_LEN; t0 += 2) {
#pragma unroll
        for (int half = 0; half < 2; half++) {
            const int t = t0 + half;
            const int cur = half;                 // compile-time buffer index
            float pv[8];
#pragma unroll
            for (int i = 0; i < 8; i++) pv[i] = pf[cur][i];
            if (t + 2 < T_LEN) {
#pragma unroll
                for (int i = 0; i < 8; i++) pf[cur][i] = pbase[i][(size_t)(t + 2) * HIDN];
            }

            bf16x8 af[8];
#pragma unroll
            for (int ks = 0; ks < 8; ks++)
                af[ks] = *(const bf16x8*)&hbuf[cur][c15][ks * 32 + q * 8];

            f32x4 a0 = f32x4{0.f, 0.f, 0.f, 0.f};
            f32x4 a1 = f32x4{0.f, 0.f, 0.f, 0.f};
#pragma unroll
            for (int ks = 0; ks < 8; ks++) {
                a0 = mfma16(af[ks], bfrag[0][ks], a0);
                a1 = mfma16(af[ks], bfrag[1][ks], a1);
            }

#pragma unroll
            for (int nt = 0; nt < 2; nt++) {
                f32x4 a = nt ? a1 : a0;
                int n = wv * 32 + nt * 16 + c15;
#pragma unroll
                for (int r = 0; r < 4; r++) {
                    float x  = a[r] + pv[nt * 4 + r];
                    float th = tanh_fast(x);
                    __bf16 hb = (__bf16)th;
                    hbuf[cur ^ 1][4 * q + r][n] = hb;          // next step's A operand
                    hbase[nt * 4 + r][(size_t)t * HIDN] = hb;  // hs for decode GEMM
                    if (t == T_LEN - 1)
                        hT[(size_t)(b0 + 4 * q + r) * HIDN + n] = th;  // fp32 tail state
                }
            }
            __syncthreads();
        }
    }
}

extern "C" void kernel_launch(void* const* d_in, const int* in_sizes, int n_in,
                              void* d_out, int out_size, void* d_ws, size_t ws_size,
                              hipStream_t stream)
{
    const int*   x   = (const int*)d_in[0];
    float*       emb = (float*)d_in[1];          // row 0 zeroed (padding_idx)
    const float* W1  = (const float*)d_in[2];    // [256][512]
    const float* b1  = (const float*)d_in[3];
    const float* Wd  = (const float*)d_in[4];    // [5000][256]
    const float* bd  = (const float*)d_in[5];
    float* out = (float*)d_out;

    // pre (fp32, 33.5MB) aliases the head of d_out: consumed by rnn_scan,
    // dead before the decode GEMM overwrites it. hs (bf16, 16.8MB) in ws.
    float*  pre = (float*)d_out;
    __bf16* hs  = (__bf16*)d_ws;

    zero_emb_row0<<<1, 256, 0, stream>>>(emb);
    // pre[b*T+t][j] = b1[j] + sum_k emb[x[b,t]][k] * W1[j][k]   (xt half of W1)
    gemm_bias<true><<<dim3(2, 256), 256, 0, stream>>>(
        (const void*)emb, x, W1, 2 * HIDN, b1, pre, HIDN, HIDN);
    rnn_scan<<<2, 512, 0, stream>>>(pre, W1, hs, out + OUT_ELEMS);

    if (ws_size >= HS_BYTES + WD_BYTES) {
        // One-time Wd->bf16 (L2-resident 2.56MB), then fast decode GEMM.
        __bf16* wdb = (__bf16*)((char*)d_ws + HS_BYTES);
        wd_convert<<<625, 256, 0, stream>>>(Wd, wdb);
        decode_gemm<<<dim3(40, 256), 256, 0, stream>>>(hs, wdb, bd, out);
    } else {
        // Fallback: previous session's decode (in-tile fp32->bf16 convert).
        gemm_bias<false><<<dim3(40, 256), 256, 0, stream>>>(
            (const void*)hs, nullptr, Wd, HIDN, bd, out, VOCAB, VOCAB);
    }
}